// Round 2
// baseline (134.843 us; speedup 1.0000x reference)
//
#include <hip/hip_runtime.h>

// Reprojection multi-rig model.
// out[i] = intrs[cam]*(p_cam.xy/p_cam.z) + pps[cam] - points_2d[i]
// where p_cam = R(q)*points_3d[pi] + t,
//       q = rel_q (x) ref_q,  t = rel_t + R(rel_q)*ref_t
// Quaternions stored [x,y,z,w]; rotation p + 2*(w*(v x p) + v x (v x p)).
//
// R2: gather tables are re-packed into d_ws by a prep kernel so the hot
// kernel does 3 dwordx4 gathers instead of 10 scalar dword gathers
// (TA address-processing was the bottleneck: 31% HBM, 12% VALU, 45us).

// ---- prep: pad points_3d (stride 3 -> 4 floats) and ref_poses (7 -> 8) ----
__global__ __launch_bounds__(256) void prep_kernel(
    const float* __restrict__ pts3, const float* __restrict__ ref,
    float* __restrict__ pts4, float* __restrict__ ref8,
    int npts_dw, int nref_dw)
{
    int t = blockIdx.x * blockDim.x + threadIdx.x;
    if (t < npts_dw) {
        unsigned q = (unsigned)t / 3u, r = (unsigned)t - 3u * q;
        pts4[4u * q + r] = pts3[t];
    } else {
        int u = t - npts_dw;
        if (u < nref_dw) {
            unsigned q = (unsigned)u / 7u, r = (unsigned)u - 7u * q;
            ref8[8u * q + r] = ref[u];
        }
    }
}

// ---- fast path: 16B-aligned vector gathers ----
__global__ __launch_bounds__(256) void reproj_fast(
    const float2* __restrict__ points_2d,
    const int*    __restrict__ camera_indices,
    const int2*   __restrict__ grouping_indices,
    const int*    __restrict__ point_indices,
    const float*  __restrict__ camera_pps,
    const float*  __restrict__ intrs,
    const float4* __restrict__ pts4,   // [NUM_PTS]   {x,y,z,pad}
    const float4* __restrict__ ref8,   // [NUM_GROUPS*2] {tx,ty,tz,qx}{qy,qz,qw,pad}
    const float*  __restrict__ rel_poses,
    float2*       __restrict__ out,
    int n)
{
    __shared__ float s_rel[56];   // 8 rel poses x 7
    __shared__ float s_pps[16];   // 8 cams x 2
    __shared__ float s_intr[16];  // 8 cams x 2
    int tid = threadIdx.x;
    if (tid < 56) s_rel[tid] = rel_poses[tid];
    if (tid < 16) { s_pps[tid] = camera_pps[tid]; s_intr[tid] = intrs[tid]; }
    __syncthreads();

    int i = blockIdx.x * blockDim.x + tid;
    if (i >= n) return;

    // Coalesced streaming loads
    int2   gm  = grouping_indices[i];
    int    pi  = point_indices[i];
    int    cam = camera_indices[i];
    float2 p2d = points_2d[i];

    // Vector gathers (issue ASAP; all 16B-aligned, no line splits)
    float4 pt = pts4[pi];
    float4 r0 = ref8[2 * gm.x];
    float4 r1 = ref8[2 * gm.x + 1];

    float rtx = r0.x, rty = r0.y, rtz = r0.z;
    float rqx = r0.w, rqy = r1.x, rqz = r1.y, rqw = r1.z;

    // rel pose from LDS (8 distinct entries, broadcast-ish)
    const float* lp = s_rel + 7 * gm.y;
    float ltx = lp[0], lty = lp[1], ltz = lp[2];
    float lqx = lp[3], lqy = lp[4], lqz = lp[5], lqw = lp[6];

    // t = rel_t + quat_rotate(rel_q, ref_t)
    float uvx = lqy * rtz - lqz * rty;
    float uvy = lqz * rtx - lqx * rtz;
    float uvz = lqx * rty - lqy * rtx;
    float uuvx = lqy * uvz - lqz * uvy;
    float uuvy = lqz * uvx - lqx * uvz;
    float uuvz = lqx * uvy - lqy * uvx;
    float tx = ltx + rtx + 2.0f * (lqw * uvx + uuvx);
    float ty = lty + rty + 2.0f * (lqw * uvy + uuvy);
    float tz = ltz + rtz + 2.0f * (lqw * uvz + uuvz);

    // q = quat_mul(rel_q, ref_q)
    float qw = lqw * rqw - (lqx * rqx + lqy * rqy + lqz * rqz);
    float qx = lqw * rqx + rqw * lqx + (lqy * rqz - lqz * rqy);
    float qy = lqw * rqy + rqw * lqy + (lqz * rqx - lqx * rqz);
    float qz = lqw * rqz + rqw * lqz + (lqx * rqy - lqy * rqx);

    float px = pt.x, py = pt.y, pz = pt.z;

    // p_cam = quat_rotate(q, p) + t
    float v2x = qy * pz - qz * py;
    float v2y = qz * px - qx * pz;
    float v2z = qx * py - qy * px;
    float w2x = qy * v2z - qz * v2y;
    float w2y = qz * v2x - qx * v2z;
    float w2z = qx * v2y - qy * v2x;
    float pcx = px + 2.0f * (qw * v2x + w2x) + tx;
    float pcy = py + 2.0f * (qw * v2y + w2y) + ty;
    float pcz = pz + 2.0f * (qw * v2z + w2z) + tz;

    float invz = 1.0f / pcz;  // IEEE divide, matches numpy
    float ux = s_intr[2 * cam]     * (pcx * invz) + s_pps[2 * cam];
    float uy = s_intr[2 * cam + 1] * (pcy * invz) + s_pps[2 * cam + 1];

    out[i] = make_float2(ux - p2d.x, uy - p2d.y);
}

// ---- fallback: round-1 kernel (scalar gathers), used only if ws too small ----
__global__ __launch_bounds__(256) void reproj_kernel(
    const float2* __restrict__ points_2d,
    const int*    __restrict__ camera_indices,
    const int2*   __restrict__ grouping_indices,
    const int*    __restrict__ point_indices,
    const float*  __restrict__ camera_pps,
    const float*  __restrict__ intrs,
    const float*  __restrict__ points_3d,
    const float*  __restrict__ ref_poses,
    const float*  __restrict__ rel_poses,
    float2*       __restrict__ out,
    int n)
{
    __shared__ float s_rel[56];
    __shared__ float s_pps[16];
    __shared__ float s_intr[16];
    int tid = threadIdx.x;
    if (tid < 56) s_rel[tid] = rel_poses[tid];
    if (tid < 16) { s_pps[tid] = camera_pps[tid]; s_intr[tid] = intrs[tid]; }
    __syncthreads();

    int i = blockIdx.x * blockDim.x + tid;
    if (i >= n) return;

    int2   gm  = grouping_indices[i];
    int    pi  = point_indices[i];
    int    cam = camera_indices[i];
    float2 p2d = points_2d[i];

    const float* rp = ref_poses + 7 * gm.x;
    float rtx = rp[0], rty = rp[1], rtz = rp[2];
    float rqx = rp[3], rqy = rp[4], rqz = rp[5], rqw = rp[6];

    const float* lp = s_rel + 7 * gm.y;
    float ltx = lp[0], lty = lp[1], ltz = lp[2];
    float lqx = lp[3], lqy = lp[4], lqz = lp[5], lqw = lp[6];

    float uvx = lqy * rtz - lqz * rty;
    float uvy = lqz * rtx - lqx * rtz;
    float uvz = lqx * rty - lqy * rtx;
    float uuvx = lqy * uvz - lqz * uvy;
    float uuvy = lqz * uvx - lqx * uvz;
    float uuvz = lqx * uvy - lqy * uvx;
    float tx = ltx + rtx + 2.0f * (lqw * uvx + uuvx);
    float ty = lty + rty + 2.0f * (lqw * uvy + uuvy);
    float tz = ltz + rtz + 2.0f * (lqw * uvz + uuvz);

    float qw = lqw * rqw - (lqx * rqx + lqy * rqy + lqz * rqz);
    float qx = lqw * rqx + rqw * lqx + (lqy * rqz - lqz * rqy);
    float qy = lqw * rqy + rqw * lqy + (lqz * rqx - lqx * rqz);
    float qz = lqw * rqz + rqw * lqz + (lqx * rqy - lqy * rqx);

    const float* pp = points_3d + 3 * pi;
    float px = pp[0], py = pp[1], pz = pp[2];

    float v2x = qy * pz - qz * py;
    float v2y = qz * px - qx * pz;
    float v2z = qx * py - qy * px;
    float w2x = qy * v2z - qz * v2y;
    float w2y = qz * v2x - qx * v2z;
    float w2z = qx * v2y - qy * v2x;
    float pcx = px + 2.0f * (qw * v2x + w2x) + tx;
    float pcy = py + 2.0f * (qw * v2y + w2y) + ty;
    float pcz = pz + 2.0f * (qw * v2z + w2z) + tz;

    float invz = 1.0f / pcz;
    float ux = s_intr[2 * cam]     * (pcx * invz) + s_pps[2 * cam];
    float uy = s_intr[2 * cam + 1] * (pcy * invz) + s_pps[2 * cam + 1];

    out[i] = make_float2(ux - p2d.x, uy - p2d.y);
}

extern "C" void kernel_launch(void* const* d_in, const int* in_sizes, int n_in,
                              void* d_out, int out_size, void* d_ws, size_t ws_size,
                              hipStream_t stream) {
    const float2* points_2d       = (const float2*)d_in[0];
    const int*    camera_indices  = (const int*)d_in[1];
    const int2*   grouping        = (const int2*)d_in[2];
    const int*    point_indices   = (const int*)d_in[3];
    const float*  camera_pps      = (const float*)d_in[4];
    const float*  intrs           = (const float*)d_in[5];
    const float*  points_3d       = (const float*)d_in[6];
    const float*  ref_poses       = (const float*)d_in[7];
    const float*  rel_poses       = (const float*)d_in[8];
    float2*       out             = (float2*)d_out;

    int n       = in_sizes[1];       // N observations
    int npts    = in_sizes[6] / 3;   // NUM_PTS
    int ngroups = in_sizes[7] / 7;   // NUM_GROUPS

    size_t need = (size_t)npts * 16 + (size_t)ngroups * 32;
    if (ws_size >= need) {
        float* pts4 = (float*)d_ws;
        float* ref8 = (float*)((char*)d_ws + (size_t)npts * 16);
        int npts_dw = npts * 3, nref_dw = ngroups * 7;
        int total = npts_dw + nref_dw;
        prep_kernel<<<(total + 255) / 256, 256, 0, stream>>>(
            points_3d, ref_poses, pts4, ref8, npts_dw, nref_dw);
        reproj_fast<<<(n + 255) / 256, 256, 0, stream>>>(
            points_2d, camera_indices, grouping, point_indices,
            camera_pps, intrs, (const float4*)pts4, (const float4*)ref8,
            rel_poses, out, n);
    } else {
        reproj_kernel<<<(n + 255) / 256, 256, 0, stream>>>(
            points_2d, camera_indices, grouping, point_indices,
            camera_pps, intrs, points_3d, ref_poses, rel_poses, out, n);
    }
}